// Round 18
// baseline (134.068 us; speedup 1.0000x reference)
//
#include <hip/hip_runtime.h>

#define D_DIM 128
#define DE_DIM 64
#define LN_EPS 1e-5f
#define LEAKY 0.2f
#define TPW 4            // tiles (of 16 edges) per wave in edge_mfma

typedef __attribute__((ext_vector_type(4))) float f32x4;
typedef __attribute__((ext_vector_type(8))) short s16x8;

static __device__ __forceinline__ unsigned short f2bf(float f) {
  unsigned int u = __float_as_uint(f);
  unsigned int r = (u + 0x7fffu + ((u >> 16) & 1u)) >> 16;
  return (unsigned short)r;
}

// ---------- fused setup: node_att (blocks < natt) + weight pre-pack + cnt zero ----------
__global__ __launch_bounds__(256) void setup_kernel(
    const float* __restrict__ h, const float* __restrict__ W_att,
    const float* __restrict__ W_rel, const float* __restrict__ W_w,
    float* __restrict__ a12, unsigned short* __restrict__ wrel_pk,
    unsigned short* __restrict__ ww_pk, int* __restrict__ cnt,
    int N, int natt_blocks)
{
  if ((int)blockIdx.x < natt_blocks) {
    int lane = threadIdx.x & 63;
    int wid = blockIdx.x * 4 + (threadIdx.x >> 6);
    if (wid >= N) return;
    const float* hr = &h[(long long)wid * D_DIM];
    float h0 = hr[lane], h1 = hr[64 + lane];
    float p[8];
#pragma unroll
    for (int hd = 0; hd < 4; ++hd) {
      p[hd]     = h0 * W_att[lane * 4 + hd]         + h1 * W_att[(64 + lane) * 4 + hd];
      p[4 + hd] = h0 * W_att[(128 + lane) * 4 + hd] + h1 * W_att[(192 + lane) * 4 + hd];
    }
#pragma unroll
    for (int j = 0; j < 8; ++j) {
      float v = p[j];
#pragma unroll
      for (int off = 32; off; off >>= 1) v += __shfl_xor(v, off);
      if (lane == 0) a12[(long long)wid * 8 + j] = v;
    }
    return;
  }
  int tid = (blockIdx.x - natt_blocks) * 256 + threadIdx.x;
  if (tid < 8192) {
    int j = tid & 7, lane = (tid >> 3) & 63, ks = (tid >> 9) & 1, dg = tid >> 10;
    int k = ks * 32 + 8 * (lane >> 4) + j;
    int col = 16 * dg + (lane & 15);
    wrel_pk[tid] = f2bf(W_rel[k * D_DIM + col]);
  } else if (tid < 73728) {
    int t2 = tid - 8192;
    int j = t2 & 7, lane = (t2 >> 3) & 63, dg = (t2 >> 9) & 7, kc = t2 >> 12;
    int c = kc * 32 + 8 * (lane >> 4) + j;
    int d = 16 * dg + (lane & 15);
    ww_pk[t2] = f2bf(W_w[(long long)(c & 127) * 512 + (c >> 7) * 128 + d]);
  } else {
    int i0 = (tid - 73728) * 4;
    if (i0 + 3 < N) {
      *reinterpret_cast<int4*>(&cnt[i0]) = make_int4(0, 0, 0, 0);
    } else {
      for (int j = 0; j < 4; ++j) if (i0 + j < N) cnt[i0 + j] = 0;
    }
  }
}

// ---------- CSR build: histogram -> hierarchical scan (scan2 folded into scan3) ----------

__global__ void hist_kernel(const int* __restrict__ dst, int* __restrict__ cnt, int E) {
  int e = blockIdx.x * blockDim.x + threadIdx.x;
  if (e < E) atomicAdd(&cnt[dst[e]], 1);
}

__global__ __launch_bounds__(256) void scan1_kernel(
    const int* __restrict__ cnt, int* __restrict__ bsum, int N)
{
  __shared__ int red[256];
  int b = blockIdx.x, tid = threadIdx.x;
  int i0 = b * 1024 + tid * 4;
  int s = 0;
  if (i0 + 3 < N) {
    int4 v = *reinterpret_cast<const int4*>(&cnt[i0]);
    s = v.x + v.y + v.z + v.w;
  } else {
#pragma unroll
    for (int j = 0; j < 4; ++j) if (i0 + j < N) s += cnt[i0 + j];
  }
  red[tid] = s;
  __syncthreads();
  for (int off = 128; off; off >>= 1) {
    if (tid < off) red[tid] += red[tid + off];
    __syncthreads();
  }
  if (tid == 0) bsum[b] = red[0];
}

// scan3: per-block exclusive scan; block offset derived from bsum in-kernel (wave 0)
__global__ __launch_bounds__(256) void scan3_kernel(
    const int* __restrict__ cnt, const int* __restrict__ bsum,
    int* __restrict__ row_ptr, int* __restrict__ cursor, int N, int nb)
{
  __shared__ int wsum[4];
  __shared__ int boff_s, total_s;
  int b = blockIdx.x, tid = threadIdx.x;
  int lane = tid & 63, wv = tid >> 6;
  if (tid < 64) {
    int v = (tid < nb) ? bsum[tid] : 0;
    int inc = v;
#pragma unroll
    for (int off = 1; off < 64; off <<= 1) {
      int t = __shfl_up(inc, off);
      if (tid >= off) inc += t;
    }
    if (tid == b) boff_s = inc - v;
    if (tid == 63) total_s = inc;
  }
  int i0 = b * 1024 + tid * 4;
  int c[4];
  int s = 0;
#pragma unroll
  for (int j = 0; j < 4; ++j) {
    int i = i0 + j;
    c[j] = (i < N) ? cnt[i] : 0;
    s += c[j];
  }
  int inc = s;
#pragma unroll
  for (int off = 1; off < 64; off <<= 1) {
    int t = __shfl_up(inc, off);
    if (lane >= off) inc += t;
  }
  if (lane == 63) wsum[wv] = inc;
  __syncthreads();
  int woff = 0;
  for (int w = 0; w < wv; ++w) woff += wsum[w];
  int excl = boff_s + woff + (inc - s);
#pragma unroll
  for (int j = 0; j < 4; ++j) {
    int i = i0 + j;
    if (i < N) { row_ptr[i] = excl; cursor[i] = excl; excl += c[j]; }
  }
  if (b == (int)gridDim.x - 1 && tid == 0) row_ptr[N] = total_s;
}

// ---------- fused edge pass + scatter + logit, LDS-pipelined (global_load_lds dbuf) ----------
// Per wave: TPW=4 consecutive 16-edge tiles. Tile t+1's 4 direct-to-LDS loads fly
// under tile t's compute. Source pre-swizzled (byte ^= (row&7)<<4, involution) so the
// stride-256B LDS reads are 2-way (free). Counted vmcnt, never 0 in the loop.
__global__ __launch_bounds__(256, 4) void edge_mfma_kernel(
    const float* __restrict__ edge_feat, const int* __restrict__ src,
    const int* __restrict__ dst, int* __restrict__ cursor,
    const unsigned short* __restrict__ wrel_pk, const float* __restrict__ b_rel,
    const float* __restrict__ ln_g, const float* __restrict__ ln_b,
    const float* __restrict__ W_att, const float* __restrict__ b_att,
    const float* __restrict__ a12,
    int* __restrict__ src_sorted, float* __restrict__ u_sorted, int E)
{
  __shared__ unsigned short Wlds[8192];     // 16 KB: W_rel fragment pack
  __shared__ float efb[4][2][1024];         // 32 KB: per-wave double-buffered ef tiles
  {
    int tid = threadIdx.x;
    const uint4* sp = reinterpret_cast<const uint4*>(wrel_pk);
    uint4* dp = reinterpret_cast<uint4*>(Wlds);
#pragma unroll
    for (int i = 0; i < 4; ++i) dp[tid + 256 * i] = sp[tid + 256 * i];
  }
  __syncthreads();

  int l = threadIdx.x & 63;
  int wv = threadIdx.x >> 6;
  long long gw = (long long)blockIdx.x * 4 + wv;     // global wave id
  long long ebase = gw * (TPW * 16);                 // first edge of this wave
  const char* efbytes = (const char*)edge_feat;
  long long maxbyte = (long long)E * (DE_DIM * 4) - 16;
  int G = l >> 4;

  // issue 4 direct-to-LDS loads for tile t into buffer buf (source pre-swizzled)
  auto issue = [&](int buf, int t) {
    long long tb = (ebase + (long long)t * 16) * (DE_DIM * 4);
#pragma unroll
    for (int i = 0; i < 4; ++i) {
      int d = i * 1024 + l * 16;                     // linear LDS dest offset
      int row = d >> 8;
      long long gofs = tb + (long long)(d ^ ((row & 7) << 4));
      if (gofs > maxbyte) gofs = maxbyte;
      __builtin_amdgcn_global_load_lds(
          (const __attribute__((address_space(1))) void*)(efbytes + gofs),
          (__attribute__((address_space(3))) void*)((char*)&efb[wv][buf][0] + i * 1024),
          16, 0, 0);
    }
  };

  f32x4 zero4 = {0.f, 0.f, 0.f, 0.f};
  issue(0, 0);
  int cur = 0;

#pragma unroll 1
  for (int t = 0; t < TPW; ++t) {
    issue(cur ^ 1, t + 1);     // t+1 == TPW: clamped dummy (retires by kernel end)
    if (t == 0) { asm volatile("s_waitcnt vmcnt(4)" ::: "memory"); }
    else        { asm volatile("s_waitcnt vmcnt(11)" ::: "memory"); }
    __builtin_amdgcn_sched_barrier(0);

    long long er = ebase + (long long)t * 16 + (l & 15);
    bool erok = (er < E);
    long long ers = erok ? er : (long long)(E - 1);
    int dN = dst[ers];
    int sN = src[ers];
    float4 ba = *reinterpret_cast<const float4*>(&b_att[0]);

    // LDS -> regs (swizzled read) + pack to bf16 fragments
    const char* eb = (const char*)&efb[wv][cur][0];
    s16x8 efrag[2];
#pragma unroll
    for (int ks = 0; ks < 2; ++ks) {
      int o = (l & 15) * 256 + ks * 128 + G * 32;
      int so = o ^ (((l & 15) & 7) << 4);
      float4 v0 = *reinterpret_cast<const float4*>(eb + so);
      float4 v1 = *reinterpret_cast<const float4*>(eb + (so ^ 16));
      s16x8 a;
      a[0] = (short)f2bf(v0.x); a[1] = (short)f2bf(v0.y);
      a[2] = (short)f2bf(v0.z); a[3] = (short)f2bf(v0.w);
      a[4] = (short)f2bf(v1.x); a[5] = (short)f2bf(v1.y);
      a[6] = (short)f2bf(v1.z); a[7] = (short)f2bf(v1.w);
      efrag[ks] = a;
    }

    f32x4 acc[8];
#pragma unroll
    for (int dg = 0; dg < 8; ++dg) acc[dg] = zero4;
#pragma unroll
    for (int dg = 0; dg < 8; ++dg) {
      s16x8 w0 = *reinterpret_cast<const s16x8*>(&Wlds[((dg * 2 + 0) * 64 + l) * 8]);
      s16x8 w1 = *reinterpret_cast<const s16x8*>(&Wlds[((dg * 2 + 1) * 64 + l) * 8]);
      acc[dg] = __builtin_amdgcn_mfma_f32_16x16x32_bf16(w0, efrag[0], acc[dg], 0, 0, 0);
      acc[dg] = __builtin_amdgcn_mfma_f32_16x16x32_bf16(w1, efrag[1], acc[dg], 0, 0, 0);
    }

    float4 a1 = *reinterpret_cast<const float4*>(&a12[(long long)dN * 8]);
    float4 a2 = *reinterpret_cast<const float4*>(&a12[(long long)sN * 8 + 4]);

    float s = 0.f, q = 0.f;
#pragma unroll
    for (int dg = 0; dg < 8; ++dg) {
      float4 br = *reinterpret_cast<const float4*>(&b_rel[16 * dg + 4 * G]);
      const float* brp = &br.x;
#pragma unroll
      for (int i = 0; i < 4; ++i) {
        float v = acc[dg][i] + brp[i];
        acc[dg][i] = v;
        s += v; q += v * v;
      }
    }
    s += __shfl_xor(s, 16); s += __shfl_xor(s, 32);
    q += __shfl_xor(q, 16); q += __shfl_xor(q, 32);
    float mu = s * (1.f / 128.f);
    float rstd = rsqrtf(q * (1.f / 128.f) - mu * mu + LN_EPS);

    float u0 = 0.f, u1 = 0.f, u2 = 0.f, u3 = 0.f;
#pragma unroll
    for (int dg = 0; dg < 8; ++dg) {
      int d0 = 16 * dg + 4 * G;
      float4 g  = *reinterpret_cast<const float4*>(&ln_g[d0]);
      float4 bb = *reinterpret_cast<const float4*>(&ln_b[d0]);
      const float* gp = &g.x; const float* bp = &bb.x;
#pragma unroll
      for (int i = 0; i < 4; ++i) {
        float w = (acc[dg][i] - mu) * rstd * gp[i] + bp[i];
        w = fmaxf(w, 0.f);
        float4 wa = *reinterpret_cast<const float4*>(&W_att[(256 + d0 + i) * 4]);
        u0 = fmaf(w, wa.x, u0);
        u1 = fmaf(w, wa.y, u1);
        u2 = fmaf(w, wa.z, u2);
        u3 = fmaf(w, wa.w, u3);
      }
    }
    u0 += __shfl_xor(u0, 16); u0 += __shfl_xor(u0, 32);
    u1 += __shfl_xor(u1, 16); u1 += __shfl_xor(u1, 32);
    u2 += __shfl_xor(u2, 16); u2 += __shfl_xor(u2, 32);
    u3 += __shfl_xor(u3, 16); u3 += __shfl_xor(u3, 32);

    if (l < 16 && erok) {
      int p = atomicAdd(&cursor[dN], 1);
      src_sorted[p] = sN;
      float4 o;
      o.x = a1.x + a2.x + u0 + ba.x; o.x = (o.x >= 0.f) ? o.x : LEAKY * o.x;
      o.y = a1.y + a2.y + u1 + ba.y; o.y = (o.y >= 0.f) ? o.y : LEAKY * o.y;
      o.z = a1.z + a2.z + u2 + ba.z; o.z = (o.z >= 0.f) ? o.z : LEAKY * o.z;
      o.w = a1.w + a2.w + u3 + ba.w; o.w = (o.w >= 0.f) ? o.w : LEAKY * o.w;
      *reinterpret_cast<float4*>(&u_sorted[(long long)p * 4]) = o;
    }
    cur ^= 1;
  }
}

// ---------- per-node segment softmax, 2-pass: u -> e (in place) + recip[n] ----------
__global__ __launch_bounds__(256) void alpha_kernel(
    const int* __restrict__ row_ptr, float* __restrict__ u_sorted,
    float* __restrict__ recip, int N)
{
  int n = blockIdx.x * blockDim.x + threadIdx.x;
  if (n >= N) return;
  int lo = row_ptr[n], hi = row_ptr[n + 1];
  if (lo == hi) return;
  float m0 = -1e30f, m1 = -1e30f, m2 = -1e30f, m3 = -1e30f;
  for (int p = lo; p < hi; ++p) {
    float4 u = *reinterpret_cast<const float4*>(&u_sorted[(long long)p * 4]);
    m0 = fmaxf(m0, u.x); m1 = fmaxf(m1, u.y);
    m2 = fmaxf(m2, u.z); m3 = fmaxf(m3, u.w);
  }
  float d0 = 0.f, d1 = 0.f, d2 = 0.f, d3 = 0.f;
  for (int p = lo; p < hi; ++p) {
    float4 u = *reinterpret_cast<float4*>(&u_sorted[(long long)p * 4]);
    float4 ev;
    ev.x = __expf(u.x - m0); ev.y = __expf(u.y - m1);
    ev.z = __expf(u.z - m2); ev.w = __expf(u.w - m3);
    d0 += ev.x; d1 += ev.y; d2 += ev.z; d3 += ev.w;
    *reinterpret_cast<float4*>(&u_sorted[(long long)p * 4]) = ev;
  }
  float4 rc = make_float4(1.f / d0, 1.f / d1, 1.f / d2, 1.f / d3);
  *reinterpret_cast<float4*>(&recip[(long long)n * 4]) = rc;
}

// ---------- fused aggregate + final GEMM (block = 32 nodes, 8 waves, t in LDS) ----------
__global__ __launch_bounds__(512) void agg_final_kernel(
    const float* __restrict__ h, const int* __restrict__ src_sorted,
    const float* __restrict__ alpha, const float* __restrict__ recip,
    const int* __restrict__ row_ptr,
    const unsigned short* __restrict__ ww_pk, const float* __restrict__ b_w,
    const float* __restrict__ prelu_a, float* __restrict__ out, int N)
{
  __shared__ unsigned short t_lds[32 * 512];   // 32 KB
  int tid = threadIdx.x;
  int l = tid & 63, wv = tid >> 6;   // wv 0..7
  int n0 = blockIdx.x * 32;
  float4 fz4 = make_float4(0.f, 0.f, 0.f, 0.f);

#pragma unroll 1
  for (int i = 0; i < 4; ++i) {
    int ln = wv * 4 + i;
    int n = n0 + ln;
    float acc[8];
#pragma unroll
    for (int j = 0; j < 8; ++j) acc[j] = 0.f;
    if (n < N) {
      int lo = row_ptr[n], hi = row_ptr[n + 1];
      if (lo < hi) {
        int s0 = src_sorted[lo];
        int s1 = (lo + 1 < hi) ? src_sorted[lo + 1] : s0;
        float4 al0 = *reinterpret_cast<const float4*>(&alpha[(long long)lo * 4]);
        float4 al1 = (lo + 1 < hi)
          ? *reinterpret_cast<const float4*>(&alpha[(long long)(lo + 1) * 4]) : fz4;
        const float* hp0 = &h[(long long)s0 * D_DIM];
        const float* hp1 = &h[(long long)s1 * D_DIM];
        float ha0 = hp0[l], ha1 = hp0[64 + l];
        float hb0 = hp1[l], hb1 = hp1[64 + l];
        for (int p = lo; p < hi; p += 2) {
          float4 cal0 = al0, cal1 = al1;
          float ca0 = ha0, ca1 = ha1, cb0 = hb0, cb1 = hb1;
          int np = p + 2;
          if (np < hi) {
            int t0 = src_sorted[np];
            int t1 = (np + 1 < hi) ? src_sorted[np + 1] : t0;
            al0 = *reinterpret_cast<const float4*>(&alpha[(long long)np * 4]);
            al1 = (np + 1 < hi)
              ? *reinterpret_cast<const float4*>(&alpha[(long long)(np + 1) * 4]) : fz4;
            const float* q0 = &h[(long long)t0 * D_DIM];
            const float* q1 = &h[(long long)t1 * D_DIM];
            ha0 = q0[l]; ha1 = q0[64 + l];
            hb0 = q1[l]; hb1 = q1[64 + l];
          }
          acc[0] = fmaf(cal0.x, ca0, acc[0]); acc[1] = fmaf(cal0.x, ca1, acc[1]);
          acc[2] = fmaf(cal0.y, ca0, acc[2]); acc[3] = fmaf(cal0.y, ca1, acc[3]);
          acc[4] = fmaf(cal0.z, ca0, acc[4]); acc[5] = fmaf(cal0.z, ca1, acc[5]);
          acc[6] = fmaf(cal0.w, ca0, acc[6]); acc[7] = fmaf(cal0.w, ca1, acc[7]);
          acc[0] = fmaf(cal1.x, cb0, acc[0]); acc[1] = fmaf(cal1.x, cb1, acc[1]);
          acc[2] = fmaf(cal1.y, cb0, acc[2]); acc[3] = fmaf(cal1.y, cb1, acc[3]);
          acc[4] = fmaf(cal1.z, cb0, acc[4]); acc[5] = fmaf(cal1.z, cb1, acc[5]);
          acc[6] = fmaf(cal1.w, cb0, acc[6]); acc[7] = fmaf(cal1.w, cb1, acc[7]);
        }
        float4 rc = *reinterpret_cast<const float4*>(&recip[(long long)n * 4]);
        acc[0] *= rc.x; acc[1] *= rc.x;
        acc[2] *= rc.y; acc[3] *= rc.y;
        acc[4] *= rc.z; acc[5] *= rc.z;
        acc[6] *= rc.w; acc[7] *= rc.w;
      }
    }
    int swz = ln & 7;
#pragma unroll
    for (int hd = 0; hd < 4; ++hd) {
      int idx0 = hd * 128 + l;
      int idx1 = hd * 128 + 64 + l;
      int sw0 = ((((idx0 >> 3) ^ swz) << 3) | (idx0 & 7));
      int sw1 = ((((idx1 >> 3) ^ swz) << 3) | (idx1 & 7));
      t_lds[ln * 512 + sw0] = f2bf(acc[2 * hd]);
      t_lds[ln * 512 + sw1] = f2bf(acc[2 * hd + 1]);
    }
  }
  __syncthreads();

  int cq = l & 15;
  int ksl = l >> 4;
  int dg = wv;
  f32x4 zero4 = {0.f, 0.f, 0.f, 0.f};
  f32x4 acc2[2];
  acc2[0] = zero4; acc2[1] = zero4;

  for (int kc = 0; kc < 16; ++kc) {
    s16x8 a0, a1;
    {
      int r0 = cq;
      int r1 = 16 + cq;
      int idx = kc * 32 + 8 * ksl;
      int sw0 = ((idx >> 3) ^ (r0 & 7)) << 3;
      int sw1 = ((idx >> 3) ^ (r1 & 7)) << 3;
      a0 = *reinterpret_cast<const s16x8*>(&t_lds[r0 * 512 + sw0]);
      a1 = *reinterpret_cast<const s16x8*>(&t_lds[r1 * 512 + sw1]);
    }
    s16x8 b = *reinterpret_cast<const s16x8*>(&ww_pk[((long long)(kc * 8 + dg) * 64 + l) * 8]);
    acc2[0] = __builtin_amdgcn_mfma_f32_16x16x32_bf16(a0, b, acc2[0], 0, 0, 0);
    acc2[1] = __builtin_amdgcn_mfma_f32_16x16x32_bf16(a1, b, acc2[1], 0, 0, 0);
  }

  float pa = prelu_a[0];
  int col = 16 * dg + cq;
  float bsv = b_w[col] + b_w[128 + col] + b_w[256 + col] + b_w[384 + col];
#pragma unroll
  for (int rg = 0; rg < 2; ++rg)
#pragma unroll
    for (int i = 0; i < 4; ++i) {
      int row = n0 + rg * 16 + 4 * ksl + i;
      if (row >= N) continue;
      bool has = row_ptr[row + 1] > row_ptr[row];
      float v = (acc2[rg][i] + bsv) * 0.25f;
      v = (v >= 0.f) ? v : pa * v;
      if (!has) v = h[(long long)row * 128 + col];
      out[(long long)row * 128 + col] = v;
    }
}

extern "C" void kernel_launch(void* const* d_in, const int* in_sizes, int n_in,
                              void* d_out, int out_size, void* d_ws, size_t ws_size,
                              hipStream_t stream)
{
  const float* h         = (const float*)d_in[0];
  const float* edge_feat = (const float*)d_in[1];
  const int*   src       = (const int*)d_in[2];
  const int*   dst       = (const int*)d_in[3];
  const float* W_rel     = (const float*)d_in[4];
  const float* b_rel     = (const float*)d_in[5];
  const float* ln_g      = (const float*)d_in[6];
  const float* ln_b      = (const float*)d_in[7];
  const float* W_att     = (const float*)d_in[8];
  const float* b_att     = (const float*)d_in[9];
  const float* W_w       = (const float*)d_in[10];
  const float* b_w       = (const float*)d_in[11];
  const float* prelu_a   = (const float*)d_in[12];

  int N = in_sizes[0] / D_DIM;
  int E = in_sizes[2];
  int nb = (N + 1023) / 1024;

  char* ws = (char*)d_ws;
  size_t off = 0;
#define ALLOC(ptr, type, count) type* ptr = (type*)(ws + off); off = (off + (size_t)(count) * sizeof(type) + 63) & ~(size_t)63;
  ALLOC(u_sorted, float, (size_t)E * 4)
  ALLOC(a12, float, (size_t)N * 8)
  ALLOC(recip, float, (size_t)N * 4)
  ALLOC(row_ptr, int, N + 1)
  ALLOC(cnt, int, N)
  ALLOC(cursor, int, N)
  ALLOC(src_sorted, int, E)
  ALLOC(wrel_pk, unsigned short, 8192)
  ALLOC(ww_pk, unsigned short, 65536)
  ALLOC(bsum, int, 64)
#undef ALLOC

  int natt_blocks = (N + 3) / 4;
  int prep_threads = 73728 + (N + 3) / 4;
  int prep_blocks = (prep_threads + 255) / 256;
  setup_kernel<<<natt_blocks + prep_blocks, 256, 0, stream>>>(
      h, W_att, W_rel, W_w, a12, wrel_pk, ww_pk, cnt, N, natt_blocks);
  hist_kernel<<<(E + 255) / 256, 256, 0, stream>>>(dst, cnt, E);
  scan1_kernel<<<nb, 256, 0, stream>>>(cnt, bsum, N);
  scan3_kernel<<<nb, 256, 0, stream>>>(cnt, bsum, row_ptr, cursor, N, nb);
  int eblocks = (E + (TPW * 16 * 4) - 1) / (TPW * 16 * 4);
  edge_mfma_kernel<<<eblocks, 256, 0, stream>>>(edge_feat, src, dst, cursor,
                                                wrel_pk, b_rel, ln_g, ln_b,
                                                W_att, b_att, a12,
                                                src_sorted, u_sorted, E);
  alpha_kernel<<<(N + 255) / 256, 256, 0, stream>>>(row_ptr, u_sorted, recip, N);
  agg_final_kernel<<<(N + 31) / 32, 512, 0, stream>>>(h, src_sorted, u_sorted, recip, row_ptr,
                                                      ww_pk, b_w, prelu_a, (float*)d_out, N);
}

// Round 19
// 122.669 us; speedup vs baseline: 1.0929x; 1.0929x over previous
//
#include <hip/hip_runtime.h>

#define D_DIM 128
#define DE_DIM 64
#define LN_EPS 1e-5f
#define LEAKY 0.2f

typedef __attribute__((ext_vector_type(4))) float f32x4;
typedef __attribute__((ext_vector_type(8))) short s16x8;

static __device__ __forceinline__ unsigned short f2bf(float f) {
  unsigned int u = __float_as_uint(f);
  unsigned int r = (u + 0x7fffu + ((u >> 16) & 1u)) >> 16;
  return (unsigned short)r;
}

// ---------- fused setup: node_att (blocks < natt) + weight pre-pack + cnt zero ----------
__global__ __launch_bounds__(256) void setup_kernel(
    const float* __restrict__ h, const float* __restrict__ W_att,
    const float* __restrict__ W_rel, const float* __restrict__ W_w,
    float* __restrict__ a12, unsigned short* __restrict__ wrel_pk,
    unsigned short* __restrict__ ww_pk, int* __restrict__ cnt,
    int N, int natt_blocks)
{
  if ((int)blockIdx.x < natt_blocks) {
    int lane = threadIdx.x & 63;
    int wid = blockIdx.x * 4 + (threadIdx.x >> 6);
    if (wid >= N) return;
    const float* hr = &h[(long long)wid * D_DIM];
    float h0 = hr[lane], h1 = hr[64 + lane];
    float p[8];
#pragma unroll
    for (int hd = 0; hd < 4; ++hd) {
      p[hd]     = h0 * W_att[lane * 4 + hd]         + h1 * W_att[(64 + lane) * 4 + hd];
      p[4 + hd] = h0 * W_att[(128 + lane) * 4 + hd] + h1 * W_att[(192 + lane) * 4 + hd];
    }
#pragma unroll
    for (int j = 0; j < 8; ++j) {
      float v = p[j];
#pragma unroll
      for (int off = 32; off; off >>= 1) v += __shfl_xor(v, off);
      if (lane == 0) a12[(long long)wid * 8 + j] = v;
    }
    return;
  }
  int tid = (blockIdx.x - natt_blocks) * 256 + threadIdx.x;
  if (tid < 8192) {
    int j = tid & 7, lane = (tid >> 3) & 63, ks = (tid >> 9) & 1, dg = tid >> 10;
    int k = ks * 32 + 8 * (lane >> 4) + j;
    int col = 16 * dg + (lane & 15);
    wrel_pk[tid] = f2bf(W_rel[k * D_DIM + col]);
  } else if (tid < 73728) {
    int t2 = tid - 8192;
    int j = t2 & 7, lane = (t2 >> 3) & 63, dg = (t2 >> 9) & 7, kc = t2 >> 12;
    int c = kc * 32 + 8 * (lane >> 4) + j;
    int d = 16 * dg + (lane & 15);
    ww_pk[t2] = f2bf(W_w[(long long)(c & 127) * 512 + (c >> 7) * 128 + d]);
  } else {
    int i0 = (tid - 73728) * 4;
    if (i0 + 3 < N) {
      *reinterpret_cast<int4*>(&cnt[i0]) = make_int4(0, 0, 0, 0);
    } else {
      for (int j = 0; j < 4; ++j) if (i0 + j < N) cnt[i0 + j] = 0;
    }
  }
}

// ---------- CSR build: histogram -> hierarchical scan (scan2 folded into scan3) ----------

__global__ void hist_kernel(const int* __restrict__ dst, int* __restrict__ cnt, int E) {
  int e = blockIdx.x * blockDim.x + threadIdx.x;
  if (e < E) atomicAdd(&cnt[dst[e]], 1);
}

__global__ __launch_bounds__(256) void scan1_kernel(
    const int* __restrict__ cnt, int* __restrict__ bsum, int N)
{
  __shared__ int red[256];
  int b = blockIdx.x, tid = threadIdx.x;
  int i0 = b * 1024 + tid * 4;
  int s = 0;
  if (i0 + 3 < N) {
    int4 v = *reinterpret_cast<const int4*>(&cnt[i0]);
    s = v.x + v.y + v.z + v.w;
  } else {
#pragma unroll
    for (int j = 0; j < 4; ++j) if (i0 + j < N) s += cnt[i0 + j];
  }
  red[tid] = s;
  __syncthreads();
  for (int off = 128; off; off >>= 1) {
    if (tid < off) red[tid] += red[tid + off];
    __syncthreads();
  }
  if (tid == 0) bsum[b] = red[0];
}

// scan3: per-block exclusive scan; block offset derived from bsum in-kernel (wave 0)
__global__ __launch_bounds__(256) void scan3_kernel(
    const int* __restrict__ cnt, const int* __restrict__ bsum,
    int* __restrict__ row_ptr, int* __restrict__ cursor, int N, int nb)
{
  __shared__ int wsum[4];
  __shared__ int boff_s, total_s;
  int b = blockIdx.x, tid = threadIdx.x;
  int lane = tid & 63, wv = tid >> 6;
  if (tid < 64) {
    int v = (tid < nb) ? bsum[tid] : 0;
    int inc = v;
#pragma unroll
    for (int off = 1; off < 64; off <<= 1) {
      int t = __shfl_up(inc, off);
      if (tid >= off) inc += t;
    }
    if (tid == b) boff_s = inc - v;
    if (tid == 63) total_s = inc;
  }
  int i0 = b * 1024 + tid * 4;
  int c[4];
  int s = 0;
#pragma unroll
  for (int j = 0; j < 4; ++j) {
    int i = i0 + j;
    c[j] = (i < N) ? cnt[i] : 0;
    s += c[j];
  }
  int inc = s;
#pragma unroll
  for (int off = 1; off < 64; off <<= 1) {
    int t = __shfl_up(inc, off);
    if (lane >= off) inc += t;
  }
  if (lane == 63) wsum[wv] = inc;
  __syncthreads();
  int woff = 0;
  for (int w = 0; w < wv; ++w) woff += wsum[w];
  int excl = boff_s + woff + (inc - s);
#pragma unroll
  for (int j = 0; j < 4; ++j) {
    int i = i0 + j;
    if (i < N) { row_ptr[i] = excl; cursor[i] = excl; excl += c[j]; }
  }
  if (b == (int)gridDim.x - 1 && tid == 0) row_ptr[N] = total_s;
}

// ---------- fused edge pass + scatter + logit; tail loads hoisted to front ----------
__global__ __launch_bounds__(512, 4) void edge_mfma_kernel(
    const float* __restrict__ edge_feat, const int* __restrict__ src,
    const int* __restrict__ dst, int* __restrict__ cursor,
    const unsigned short* __restrict__ wrel_pk, const float* __restrict__ b_rel,
    const float* __restrict__ ln_g, const float* __restrict__ ln_b,
    const float* __restrict__ W_att, const float* __restrict__ b_att,
    const float* __restrict__ a12,
    int* __restrict__ src_sorted, float* __restrict__ u_sorted, int E)
{
  __shared__ unsigned short Wlds[8192];   // 16 KB: full W_rel fragment pack
  {
    int tid = threadIdx.x;               // 512 threads: 2 x uint4 each
    const uint4* sp = reinterpret_cast<const uint4*>(wrel_pk);
    uint4* dp = reinterpret_cast<uint4*>(Wlds);
    dp[tid] = sp[tid];
    dp[tid + 512] = sp[tid + 512];
  }
  __syncthreads();

  int l = threadIdx.x & 63;
  int wv = threadIdx.x >> 6;             // 0..7
  long long e0 = (long long)blockIdx.x * 128 + wv * 16;

  long long er = e0 + (l & 15);
  bool erok = (er < E);
  long long ers = erok ? er : (long long)(E - 1);

  // HOIST 1: dst/src for the tail — independent, issue first (hide under MFMA)
  int dN = dst[ers];
  int sN = src[ers];
  float4 ba = *reinterpret_cast<const float4*>(&b_att[0]);

  const float* ef = &edge_feat[er * DE_DIM + 8 * (l >> 4)];
  s16x8 efrag[2];
#pragma unroll
  for (int ks = 0; ks < 2; ++ks) {
    s16x8 a;
    if (erok) {
      float4 v0 = *reinterpret_cast<const float4*>(&ef[ks * 32]);
      float4 v1 = *reinterpret_cast<const float4*>(&ef[ks * 32 + 4]);
      a[0] = (short)f2bf(v0.x); a[1] = (short)f2bf(v0.y);
      a[2] = (short)f2bf(v0.z); a[3] = (short)f2bf(v0.w);
      a[4] = (short)f2bf(v1.x); a[5] = (short)f2bf(v1.y);
      a[6] = (short)f2bf(v1.z); a[7] = (short)f2bf(v1.w);
    } else {
#pragma unroll
      for (int j = 0; j < 8; ++j) a[j] = 0;
    }
    efrag[ks] = a;
  }

  f32x4 zero4 = {0.f, 0.f, 0.f, 0.f};
  f32x4 acc[8];
#pragma unroll
  for (int dg = 0; dg < 8; ++dg) acc[dg] = zero4;

#pragma unroll
  for (int dg = 0; dg < 8; ++dg) {
    s16x8 w0 = *reinterpret_cast<const s16x8*>(&Wlds[((dg * 2 + 0) * 64 + l) * 8]);
    s16x8 w1 = *reinterpret_cast<const s16x8*>(&Wlds[((dg * 2 + 1) * 64 + l) * 8]);
    acc[dg] = __builtin_amdgcn_mfma_f32_16x16x32_bf16(w0, efrag[0], acc[dg], 0, 0, 0);
    acc[dg] = __builtin_amdgcn_mfma_f32_16x16x32_bf16(w1, efrag[1], acc[dg], 0, 0, 0);
  }

  // HOIST 2: a12 gathers (depend only on dN/sN) — issue before LN tail (hide under VALU)
  float4 a1 = *reinterpret_cast<const float4*>(&a12[(long long)dN * 8]);
  float4 a2 = *reinterpret_cast<const float4*>(&a12[(long long)sN * 8 + 4]);

  int G = l >> 4;
  float s = 0.f, q = 0.f;
#pragma unroll
  for (int dg = 0; dg < 8; ++dg) {
    float4 br = *reinterpret_cast<const float4*>(&b_rel[16 * dg + 4 * G]);
    const float* brp = &br.x;
#pragma unroll
    for (int i = 0; i < 4; ++i) {
      float v = acc[dg][i] + brp[i];
      acc[dg][i] = v;
      s += v; q += v * v;
    }
  }
  s += __shfl_xor(s, 16); s += __shfl_xor(s, 32);
  q += __shfl_xor(q, 16); q += __shfl_xor(q, 32);
  float mu = s * (1.f / 128.f);
  float var = q * (1.f / 128.f) - mu * mu;
  float rstd = rsqrtf(var + LN_EPS);

  float u0 = 0.f, u1 = 0.f, u2 = 0.f, u3 = 0.f;
#pragma unroll
  for (int dg = 0; dg < 8; ++dg) {
    int d0 = 16 * dg + 4 * G;
    float4 g  = *reinterpret_cast<const float4*>(&ln_g[d0]);
    float4 bb = *reinterpret_cast<const float4*>(&ln_b[d0]);
    const float* gp = &g.x; const float* bp = &bb.x;
#pragma unroll
    for (int i = 0; i < 4; ++i) {
      float w = (acc[dg][i] - mu) * rstd * gp[i] + bp[i];
      w = fmaxf(w, 0.f);
      float4 wa = *reinterpret_cast<const float4*>(&W_att[(256 + d0 + i) * 4]);
      u0 = fmaf(w, wa.x, u0);
      u1 = fmaf(w, wa.y, u1);
      u2 = fmaf(w, wa.z, u2);
      u3 = fmaf(w, wa.w, u3);
    }
  }
  u0 += __shfl_xor(u0, 16); u0 += __shfl_xor(u0, 32);
  u1 += __shfl_xor(u1, 16); u1 += __shfl_xor(u1, 32);
  u2 += __shfl_xor(u2, 16); u2 += __shfl_xor(u2, 32);
  u3 += __shfl_xor(u3, 16); u3 += __shfl_xor(u3, 32);

  // tail: only atomic + scattered store remain dependent
  if (l < 16 && erok) {
    int p = atomicAdd(&cursor[dN], 1);
    src_sorted[p] = sN;
    float4 o;
    o.x = a1.x + a2.x + u0 + ba.x; o.x = (o.x >= 0.f) ? o.x : LEAKY * o.x;
    o.y = a1.y + a2.y + u1 + ba.y; o.y = (o.y >= 0.f) ? o.y : LEAKY * o.y;
    o.z = a1.z + a2.z + u2 + ba.z; o.z = (o.z >= 0.f) ? o.z : LEAKY * o.z;
    o.w = a1.w + a2.w + u3 + ba.w; o.w = (o.w >= 0.f) ? o.w : LEAKY * o.w;
    *reinterpret_cast<float4*>(&u_sorted[(long long)p * 4]) = o;
  }
}

// ---------- per-node segment softmax, 2-pass: u -> e (in place) + recip[n] ----------
__global__ __launch_bounds__(256) void alpha_kernel(
    const int* __restrict__ row_ptr, float* __restrict__ u_sorted,
    float* __restrict__ recip, int N)
{
  int n = blockIdx.x * blockDim.x + threadIdx.x;
  if (n >= N) return;
  int lo = row_ptr[n], hi = row_ptr[n + 1];
  if (lo == hi) return;
  float m0 = -1e30f, m1 = -1e30f, m2 = -1e30f, m3 = -1e30f;
  for (int p = lo; p < hi; ++p) {
    float4 u = *reinterpret_cast<const float4*>(&u_sorted[(long long)p * 4]);
    m0 = fmaxf(m0, u.x); m1 = fmaxf(m1, u.y);
    m2 = fmaxf(m2, u.z); m3 = fmaxf(m3, u.w);
  }
  float d0 = 0.f, d1 = 0.f, d2 = 0.f, d3 = 0.f;
  for (int p = lo; p < hi; ++p) {
    float4 u = *reinterpret_cast<float4*>(&u_sorted[(long long)p * 4]);
    float4 ev;
    ev.x = __expf(u.x - m0); ev.y = __expf(u.y - m1);
    ev.z = __expf(u.z - m2); ev.w = __expf(u.w - m3);
    d0 += ev.x; d1 += ev.y; d2 += ev.z; d3 += ev.w;
    *reinterpret_cast<float4*>(&u_sorted[(long long)p * 4]) = ev;
  }
  float4 rc = make_float4(1.f / d0, 1.f / d1, 1.f / d2, 1.f / d3);
  *reinterpret_cast<float4*>(&recip[(long long)n * 4]) = rc;
}

// ---------- fused aggregate + final GEMM (block = 32 nodes, 8 waves, t in LDS) ----------
__global__ __launch_bounds__(512) void agg_final_kernel(
    const float* __restrict__ h, const int* __restrict__ src_sorted,
    const float* __restrict__ alpha, const float* __restrict__ recip,
    const int* __restrict__ row_ptr,
    const unsigned short* __restrict__ ww_pk, const float* __restrict__ b_w,
    const float* __restrict__ prelu_a, float* __restrict__ out, int N)
{
  __shared__ unsigned short t_lds[32 * 512];   // 32 KB
  int tid = threadIdx.x;
  int l = tid & 63, wv = tid >> 6;   // wv 0..7
  int n0 = blockIdx.x * 32;
  float4 fz4 = make_float4(0.f, 0.f, 0.f, 0.f);

  // ---- phase 1: 4 nodes per wave, 2-edge-pair pipelined gather ----
#pragma unroll 1
  for (int i = 0; i < 4; ++i) {
    int ln = wv * 4 + i;
    int n = n0 + ln;
    float acc[8];
#pragma unroll
    for (int j = 0; j < 8; ++j) acc[j] = 0.f;
    if (n < N) {
      int lo = row_ptr[n], hi = row_ptr[n + 1];
      if (lo < hi) {
        int s0 = src_sorted[lo];
        int s1 = (lo + 1 < hi) ? src_sorted[lo + 1] : s0;
        float4 al0 = *reinterpret_cast<const float4*>(&alpha[(long long)lo * 4]);
        float4 al1 = (lo + 1 < hi)
          ? *reinterpret_cast<const float4*>(&alpha[(long long)(lo + 1) * 4]) : fz4;
        const float* hp0 = &h[(long long)s0 * D_DIM];
        const float* hp1 = &h[(long long)s1 * D_DIM];
        float ha0 = hp0[l], ha1 = hp0[64 + l];
        float hb0 = hp1[l], hb1 = hp1[64 + l];
        for (int p = lo; p < hi; p += 2) {
          float4 cal0 = al0, cal1 = al1;
          float ca0 = ha0, ca1 = ha1, cb0 = hb0, cb1 = hb1;
          int np = p + 2;
          if (np < hi) {
            int t0 = src_sorted[np];
            int t1 = (np + 1 < hi) ? src_sorted[np + 1] : t0;
            al0 = *reinterpret_cast<const float4*>(&alpha[(long long)np * 4]);
            al1 = (np + 1 < hi)
              ? *reinterpret_cast<const float4*>(&alpha[(long long)(np + 1) * 4]) : fz4;
            const float* q0 = &h[(long long)t0 * D_DIM];
            const float* q1 = &h[(long long)t1 * D_DIM];
            ha0 = q0[l]; ha1 = q0[64 + l];
            hb0 = q1[l]; hb1 = q1[64 + l];
          }
          acc[0] = fmaf(cal0.x, ca0, acc[0]); acc[1] = fmaf(cal0.x, ca1, acc[1]);
          acc[2] = fmaf(cal0.y, ca0, acc[2]); acc[3] = fmaf(cal0.y, ca1, acc[3]);
          acc[4] = fmaf(cal0.z, ca0, acc[4]); acc[5] = fmaf(cal0.z, ca1, acc[5]);
          acc[6] = fmaf(cal0.w, ca0, acc[6]); acc[7] = fmaf(cal0.w, ca1, acc[7]);
          acc[0] = fmaf(cal1.x, cb0, acc[0]); acc[1] = fmaf(cal1.x, cb1, acc[1]);
          acc[2] = fmaf(cal1.y, cb0, acc[2]); acc[3] = fmaf(cal1.y, cb1, acc[3]);
          acc[4] = fmaf(cal1.z, cb0, acc[4]); acc[5] = fmaf(cal1.z, cb1, acc[5]);
          acc[6] = fmaf(cal1.w, cb0, acc[6]); acc[7] = fmaf(cal1.w, cb1, acc[7]);
        }
        // deferred softmax normalization
        float4 rc = *reinterpret_cast<const float4*>(&recip[(long long)n * 4]);
        acc[0] *= rc.x; acc[1] *= rc.x;
        acc[2] *= rc.y; acc[3] *= rc.y;
        acc[4] *= rc.z; acc[5] *= rc.z;
        acc[6] *= rc.w; acc[7] *= rc.w;
      }
    }
    int swz = ln & 7;
#pragma unroll
    for (int hd = 0; hd < 4; ++hd) {
      int idx0 = hd * 128 + l;
      int idx1 = hd * 128 + 64 + l;
      int sw0 = ((((idx0 >> 3) ^ swz) << 3) | (idx0 & 7));
      int sw1 = ((((idx1 >> 3) ^ swz) << 3) | (idx1 & 7));
      t_lds[ln * 512 + sw0] = f2bf(acc[2 * hd]);
      t_lds[ln * 512 + sw1] = f2bf(acc[2 * hd + 1]);
    }
  }
  __syncthreads();

  // ---- phase 2: GEMM 32x512 @ 512x128, wave wv owns dg = wv ----
  int cq = l & 15;
  int ksl = l >> 4;
  int dg = wv;
  f32x4 zero4 = {0.f, 0.f, 0.f, 0.f};
  f32x4 acc2[2];
  acc2[0] = zero4; acc2[1] = zero4;

  for (int kc = 0; kc < 16; ++kc) {
    s16x8 a0, a1;
    {
      int r0 = cq;
      int r1 = 16 + cq;
      int idx = kc * 32 + 8 * ksl;                 // 16B-aligned
      int sw0 = ((idx >> 3) ^ (r0 & 7)) << 3;
      int sw1 = ((idx >> 3) ^ (r1 & 7)) << 3;
      a0 = *reinterpret_cast<const s16x8*>(&t_lds[r0 * 512 + sw0]);
      a1 = *reinterpret_cast<const s16x8*>(&t_lds[r1 * 512 + sw1]);
    }
    s16x8 b = *reinterpret_cast<const s16x8*>(&ww_pk[((long long)(kc * 8 + dg) * 64 + l) * 8]);
    acc2[0] = __builtin_amdgcn_mfma_f32_16x16x32_bf16(a0, b, acc2[0], 0, 0, 0);
    acc2[1] = __builtin_amdgcn_mfma_f32_16x16x32_bf16(a1, b, acc2[1], 0, 0, 0);
  }

  float pa = prelu_a[0];
  int col = 16 * dg + cq;
  float bsv = b_w[col] + b_w[128 + col] + b_w[256 + col] + b_w[384 + col];
#pragma unroll
  for (int rg = 0; rg < 2; ++rg)
#pragma unroll
    for (int i = 0; i < 4; ++i) {
      int row = n0 + rg * 16 + 4 * ksl + i;
      if (row >= N) continue;
      bool has = row_ptr[row + 1] > row_ptr[row];
      float v = (acc2[rg][i] + bsv) * 0.25f;
      v = (v >= 0.f) ? v : pa * v;
      if (!has) v = h[(long long)row * 128 + col];
      out[(long long)row * 128 + col] = v;
    }
}

extern "C" void kernel_launch(void* const* d_in, const int* in_sizes, int n_in,
                              void* d_out, int out_size, void* d_ws, size_t ws_size,
                              hipStream_t stream)
{
  const float* h         = (const float*)d_in[0];
  const float* edge_feat = (const float*)d_in[1];
  const int*   src       = (const int*)d_in[2];
  const int*   dst       = (const int*)d_in[3];
  const float* W_rel     = (const float*)d_in[4];
  const float* b_rel     = (const float*)d_in[5];
  const float* ln_g      = (const float*)d_in[6];
  const float* ln_b      = (const float*)d_in[7];
  const float* W_att     = (const float*)d_in[8];
  const float* b_att     = (const float*)d_in[9];
  const float* W_w       = (const float*)d_in[10];
  const float* b_w       = (const float*)d_in[11];
  const float* prelu_a   = (const float*)d_in[12];

  int N = in_sizes[0] / D_DIM;
  int E = in_sizes[2];
  int nb = (N + 1023) / 1024;

  char* ws = (char*)d_ws;
  size_t off = 0;
#define ALLOC(ptr, type, count) type* ptr = (type*)(ws + off); off = (off + (size_t)(count) * sizeof(type) + 63) & ~(size_t)63;
  ALLOC(u_sorted, float, (size_t)E * 4)
  ALLOC(a12, float, (size_t)N * 8)
  ALLOC(recip, float, (size_t)N * 4)
  ALLOC(row_ptr, int, N + 1)
  ALLOC(cnt, int, N)
  ALLOC(cursor, int, N)
  ALLOC(src_sorted, int, E)
  ALLOC(wrel_pk, unsigned short, 8192)
  ALLOC(ww_pk, unsigned short, 65536)
  ALLOC(bsum, int, 64)
#undef ALLOC

  int natt_blocks = (N + 3) / 4;
  int prep_threads = 73728 + (N + 3) / 4;
  int prep_blocks = (prep_threads + 255) / 256;
  setup_kernel<<<natt_blocks + prep_blocks, 256, 0, stream>>>(
      h, W_att, W_rel, W_w, a12, wrel_pk, ww_pk, cnt, N, natt_blocks);
  hist_kernel<<<(E + 255) / 256, 256, 0, stream>>>(dst, cnt, E);
  scan1_kernel<<<nb, 256, 0, stream>>>(cnt, bsum, N);
  scan3_kernel<<<nb, 256, 0, stream>>>(cnt, bsum, row_ptr, cursor, N, nb);
  edge_mfma_kernel<<<(E + 127) / 128, 512, 0, stream>>>(edge_feat, src, dst, cursor,
                                                        wrel_pk, b_rel, ln_g, ln_b,
                                                        W_att, b_att, a12,
                                                        src_sorted, u_sorted, E);
  alpha_kernel<<<(N + 255) / 256, 256, 0, stream>>>(row_ptr, u_sorted, recip, N);
  agg_final_kernel<<<(N + 31) / 32, 512, 0, stream>>>(h, src_sorted, u_sorted, recip, row_ptr,
                                                      ww_pk, b_w, prelu_a, (float*)d_out, N);
}

// Round 20
// 120.507 us; speedup vs baseline: 1.1125x; 1.0179x over previous
//
#include <hip/hip_runtime.h>

#define D_DIM 128
#define DE_DIM 64
#define LN_EPS 1e-5f
#define LEAKY 0.2f

typedef __attribute__((ext_vector_type(4))) float f32x4;
typedef __attribute__((ext_vector_type(8))) short s16x8;

static __device__ __forceinline__ unsigned short f2bf(float f) {
  unsigned int u = __float_as_uint(f);
  unsigned int r = (u + 0x7fffu + ((u >> 16) & 1u)) >> 16;
  return (unsigned short)r;
}

// ---------- fused setup: node_att (blocks < natt) + weight pre-pack + cnt zero ----------
__global__ __launch_bounds__(256) void setup_kernel(
    const float* __restrict__ h, const float* __restrict__ W_att,
    const float* __restrict__ W_rel, const float* __restrict__ W_w,
    float* __restrict__ a12, unsigned short* __restrict__ wrel_pk,
    unsigned short* __restrict__ ww_pk, int* __restrict__ cnt,
    int N, int natt_blocks)
{
  if ((int)blockIdx.x < natt_blocks) {
    int lane = threadIdx.x & 63;
    int wid = blockIdx.x * 4 + (threadIdx.x >> 6);
    if (wid >= N) return;
    const float* hr = &h[(long long)wid * D_DIM];
    float h0 = hr[lane], h1 = hr[64 + lane];
    float p[8];
#pragma unroll
    for (int hd = 0; hd < 4; ++hd) {
      p[hd]     = h0 * W_att[lane * 4 + hd]         + h1 * W_att[(64 + lane) * 4 + hd];
      p[4 + hd] = h0 * W_att[(128 + lane) * 4 + hd] + h1 * W_att[(192 + lane) * 4 + hd];
    }
#pragma unroll
    for (int j = 0; j < 8; ++j) {
      float v = p[j];
#pragma unroll
      for (int off = 32; off; off >>= 1) v += __shfl_xor(v, off);
      if (lane == 0) a12[(long long)wid * 8 + j] = v;
    }
    return;
  }
  int tid = (blockIdx.x - natt_blocks) * 256 + threadIdx.x;
  if (tid < 8192) {
    int j = tid & 7, lane = (tid >> 3) & 63, ks = (tid >> 9) & 1, dg = tid >> 10;
    int k = ks * 32 + 8 * (lane >> 4) + j;
    int col = 16 * dg + (lane & 15);
    wrel_pk[tid] = f2bf(W_rel[k * D_DIM + col]);
  } else if (tid < 73728) {
    int t2 = tid - 8192;
    int j = t2 & 7, lane = (t2 >> 3) & 63, dg = (t2 >> 9) & 7, kc = t2 >> 12;
    int c = kc * 32 + 8 * (lane >> 4) + j;
    int d = 16 * dg + (lane & 15);
    ww_pk[t2] = f2bf(W_w[(long long)(c & 127) * 512 + (c >> 7) * 128 + d]);
  } else {
    int i0 = (tid - 73728) * 4;
    if (i0 + 3 < N) {
      *reinterpret_cast<int4*>(&cnt[i0]) = make_int4(0, 0, 0, 0);
    } else {
      for (int j = 0; j < 4; ++j) if (i0 + j < N) cnt[i0 + j] = 0;
    }
  }
}

// ---------- CSR build: histogram (stores per-edge rank) -> hierarchical scan ----------

__global__ void hist_kernel(const int* __restrict__ dst, int* __restrict__ cnt,
                            int* __restrict__ rank, int E) {
  int e = blockIdx.x * blockDim.x + threadIdx.x;
  if (e < E) rank[e] = atomicAdd(&cnt[dst[e]], 1);
}

__global__ __launch_bounds__(256) void scan1_kernel(
    const int* __restrict__ cnt, int* __restrict__ bsum, int N)
{
  __shared__ int red[256];
  int b = blockIdx.x, tid = threadIdx.x;
  int i0 = b * 1024 + tid * 4;
  int s = 0;
  if (i0 + 3 < N) {
    int4 v = *reinterpret_cast<const int4*>(&cnt[i0]);
    s = v.x + v.y + v.z + v.w;
  } else {
#pragma unroll
    for (int j = 0; j < 4; ++j) if (i0 + j < N) s += cnt[i0 + j];
  }
  red[tid] = s;
  __syncthreads();
  for (int off = 128; off; off >>= 1) {
    if (tid < off) red[tid] += red[tid + off];
    __syncthreads();
  }
  if (tid == 0) bsum[b] = red[0];
}

// scan3: per-block exclusive scan; block offset derived from bsum in-kernel (wave 0)
__global__ __launch_bounds__(256) void scan3_kernel(
    const int* __restrict__ cnt, const int* __restrict__ bsum,
    int* __restrict__ row_ptr, int N, int nb)
{
  __shared__ int wsum[4];
  __shared__ int boff_s, total_s;
  int b = blockIdx.x, tid = threadIdx.x;
  int lane = tid & 63, wv = tid >> 6;
  if (tid < 64) {
    int v = (tid < nb) ? bsum[tid] : 0;
    int inc = v;
#pragma unroll
    for (int off = 1; off < 64; off <<= 1) {
      int t = __shfl_up(inc, off);
      if (tid >= off) inc += t;
    }
    if (tid == b) boff_s = inc - v;
    if (tid == 63) total_s = inc;
  }
  int i0 = b * 1024 + tid * 4;
  int c[4];
  int s = 0;
#pragma unroll
  for (int j = 0; j < 4; ++j) {
    int i = i0 + j;
    c[j] = (i < N) ? cnt[i] : 0;
    s += c[j];
  }
  int inc = s;
#pragma unroll
  for (int off = 1; off < 64; off <<= 1) {
    int t = __shfl_up(inc, off);
    if (lane >= off) inc += t;
  }
  if (lane == 63) wsum[wv] = inc;
  __syncthreads();
  int woff = 0;
  for (int w = 0; w < wv; ++w) woff += wsum[w];
  int excl = boff_s + woff + (inc - s);
#pragma unroll
  for (int j = 0; j < 4; ++j) {
    int i = i0 + j;
    if (i < N) { row_ptr[i] = excl; excl += c[j]; }
  }
  if (b == (int)gridDim.x - 1 && tid == 0) row_ptr[N] = total_s;
}

// ---------- fused edge pass + scatter + logit; atomic-free tail via precomputed rank ----------
__global__ __launch_bounds__(512, 4) void edge_mfma_kernel(
    const float* __restrict__ edge_feat, const int* __restrict__ src,
    const int* __restrict__ dst, const int* __restrict__ rank,
    const int* __restrict__ row_ptr,
    const unsigned short* __restrict__ wrel_pk, const float* __restrict__ b_rel,
    const float* __restrict__ ln_g, const float* __restrict__ ln_b,
    const float* __restrict__ W_att, const float* __restrict__ b_att,
    const float* __restrict__ a12,
    int* __restrict__ src_sorted, float* __restrict__ u_sorted, int E)
{
  __shared__ unsigned short Wlds[8192];   // 16 KB: full W_rel fragment pack
  {
    int tid = threadIdx.x;               // 512 threads: 2 x uint4 each
    const uint4* sp = reinterpret_cast<const uint4*>(wrel_pk);
    uint4* dp = reinterpret_cast<uint4*>(Wlds);
    dp[tid] = sp[tid];
    dp[tid + 512] = sp[tid + 512];
  }
  __syncthreads();

  int l = threadIdx.x & 63;
  int wv = threadIdx.x >> 6;             // 0..7
  long long e0 = (long long)blockIdx.x * 128 + wv * 16;

  long long er = e0 + (l & 15);
  bool erok = (er < E);
  long long ers = erok ? er : (long long)(E - 1);

  // HOIST 1: dst/src/rank for the tail — independent, issue first (hide under MFMA)
  int dN = dst[ers];
  int sN = src[ers];
  int rk = rank[ers];
  float4 ba = *reinterpret_cast<const float4*>(&b_att[0]);

  const float* ef = &edge_feat[er * DE_DIM + 8 * (l >> 4)];
  s16x8 efrag[2];
#pragma unroll
  for (int ks = 0; ks < 2; ++ks) {
    s16x8 a;
    if (erok) {
      float4 v0 = *reinterpret_cast<const float4*>(&ef[ks * 32]);
      float4 v1 = *reinterpret_cast<const float4*>(&ef[ks * 32 + 4]);
      a[0] = (short)f2bf(v0.x); a[1] = (short)f2bf(v0.y);
      a[2] = (short)f2bf(v0.z); a[3] = (short)f2bf(v0.w);
      a[4] = (short)f2bf(v1.x); a[5] = (short)f2bf(v1.y);
      a[6] = (short)f2bf(v1.z); a[7] = (short)f2bf(v1.w);
    } else {
#pragma unroll
      for (int j = 0; j < 8; ++j) a[j] = 0;
    }
    efrag[ks] = a;
  }

  f32x4 zero4 = {0.f, 0.f, 0.f, 0.f};
  f32x4 acc[8];
#pragma unroll
  for (int dg = 0; dg < 8; ++dg) acc[dg] = zero4;

#pragma unroll
  for (int dg = 0; dg < 8; ++dg) {
    s16x8 w0 = *reinterpret_cast<const s16x8*>(&Wlds[((dg * 2 + 0) * 64 + l) * 8]);
    s16x8 w1 = *reinterpret_cast<const s16x8*>(&Wlds[((dg * 2 + 1) * 64 + l) * 8]);
    acc[dg] = __builtin_amdgcn_mfma_f32_16x16x32_bf16(w0, efrag[0], acc[dg], 0, 0, 0);
    acc[dg] = __builtin_amdgcn_mfma_f32_16x16x32_bf16(w1, efrag[1], acc[dg], 0, 0, 0);
  }

  // HOIST 2: a12 + row_ptr gathers (depend only on dN/sN) — hide under LN/attention VALU
  float4 a1 = *reinterpret_cast<const float4*>(&a12[(long long)dN * 8]);
  float4 a2 = *reinterpret_cast<const float4*>(&a12[(long long)sN * 8 + 4]);
  int p = row_ptr[dN] + rk;

  int G = l >> 4;
  float s = 0.f, q = 0.f;
#pragma unroll
  for (int dg = 0; dg < 8; ++dg) {
    float4 br = *reinterpret_cast<const float4*>(&b_rel[16 * dg + 4 * G]);
    const float* brp = &br.x;
#pragma unroll
    for (int i = 0; i < 4; ++i) {
      float v = acc[dg][i] + brp[i];
      acc[dg][i] = v;
      s += v; q += v * v;
    }
  }
  s += __shfl_xor(s, 16); s += __shfl_xor(s, 32);
  q += __shfl_xor(q, 16); q += __shfl_xor(q, 32);
  float mu = s * (1.f / 128.f);
  float var = q * (1.f / 128.f) - mu * mu;
  float rstd = rsqrtf(var + LN_EPS);

  float u0 = 0.f, u1 = 0.f, u2 = 0.f, u3 = 0.f;
#pragma unroll
  for (int dg = 0; dg < 8; ++dg) {
    int d0 = 16 * dg + 4 * G;
    float4 g  = *reinterpret_cast<const float4*>(&ln_g[d0]);
    float4 bb = *reinterpret_cast<const float4*>(&ln_b[d0]);
    const float* gp = &g.x; const float* bp = &bb.x;
#pragma unroll
    for (int i = 0; i < 4; ++i) {
      float w = (acc[dg][i] - mu) * rstd * gp[i] + bp[i];
      w = fmaxf(w, 0.f);
      float4 wa = *reinterpret_cast<const float4*>(&W_att[(256 + d0 + i) * 4]);
      u0 = fmaf(w, wa.x, u0);
      u1 = fmaf(w, wa.y, u1);
      u2 = fmaf(w, wa.z, u2);
      u3 = fmaf(w, wa.w, u3);
    }
  }
  u0 += __shfl_xor(u0, 16); u0 += __shfl_xor(u0, 32);
  u1 += __shfl_xor(u1, 16); u1 += __shfl_xor(u1, 32);
  u2 += __shfl_xor(u2, 16); u2 += __shfl_xor(u2, 32);
  u3 += __shfl_xor(u3, 16); u3 += __shfl_xor(u3, 32);

  // tail: pure stores (no atomic)
  if (l < 16 && erok) {
    src_sorted[p] = sN;
    float4 o;
    o.x = a1.x + a2.x + u0 + ba.x; o.x = (o.x >= 0.f) ? o.x : LEAKY * o.x;
    o.y = a1.y + a2.y + u1 + ba.y; o.y = (o.y >= 0.f) ? o.y : LEAKY * o.y;
    o.z = a1.z + a2.z + u2 + ba.z; o.z = (o.z >= 0.f) ? o.z : LEAKY * o.z;
    o.w = a1.w + a2.w + u3 + ba.w; o.w = (o.w >= 0.f) ? o.w : LEAKY * o.w;
    *reinterpret_cast<float4*>(&u_sorted[(long long)p * 4]) = o;
  }
}

// ---------- per-node segment softmax, 2-pass: u -> e (in place) + recip[n] ----------
__global__ __launch_bounds__(256) void alpha_kernel(
    const int* __restrict__ row_ptr, float* __restrict__ u_sorted,
    float* __restrict__ recip, int N)
{
  int n = blockIdx.x * blockDim.x + threadIdx.x;
  if (n >= N) return;
  int lo = row_ptr[n], hi = row_ptr[n + 1];
  if (lo == hi) return;
  float m0 = -1e30f, m1 = -1e30f, m2 = -1e30f, m3 = -1e30f;
  for (int p = lo; p < hi; ++p) {
    float4 u = *reinterpret_cast<const float4*>(&u_sorted[(long long)p * 4]);
    m0 = fmaxf(m0, u.x); m1 = fmaxf(m1, u.y);
    m2 = fmaxf(m2, u.z); m3 = fmaxf(m3, u.w);
  }
  float d0 = 0.f, d1 = 0.f, d2 = 0.f, d3 = 0.f;
  for (int p = lo; p < hi; ++p) {
    float4 u = *reinterpret_cast<float4*>(&u_sorted[(long long)p * 4]);
    float4 ev;
    ev.x = __expf(u.x - m0); ev.y = __expf(u.y - m1);
    ev.z = __expf(u.z - m2); ev.w = __expf(u.w - m3);
    d0 += ev.x; d1 += ev.y; d2 += ev.z; d3 += ev.w;
    *reinterpret_cast<float4*>(&u_sorted[(long long)p * 4]) = ev;
  }
  float4 rc = make_float4(1.f / d0, 1.f / d1, 1.f / d2, 1.f / d3);
  *reinterpret_cast<float4*>(&recip[(long long)n * 4]) = rc;
}

// ---------- fused aggregate + final GEMM (block = 32 nodes, 8 waves, t in LDS) ----------
__global__ __launch_bounds__(512) void agg_final_kernel(
    const float* __restrict__ h, const int* __restrict__ src_sorted,
    const float* __restrict__ alpha, const float* __restrict__ recip,
    const int* __restrict__ row_ptr,
    const unsigned short* __restrict__ ww_pk, const float* __restrict__ b_w,
    const float* __restrict__ prelu_a, float* __restrict__ out, int N)
{
  __shared__ unsigned short t_lds[32 * 512];   // 32 KB
  int tid = threadIdx.x;
  int l = tid & 63, wv = tid >> 6;   // wv 0..7
  int n0 = blockIdx.x * 32;
  float4 fz4 = make_float4(0.f, 0.f, 0.f, 0.f);

  // ---- phase 1: 4 nodes per wave, 2-edge-pair pipelined gather ----
#pragma unroll 1
  for (int i = 0; i < 4; ++i) {
    int ln = wv * 4 + i;
    int n = n0 + ln;
    float acc[8];
#pragma unroll
    for (int j = 0; j < 8; ++j) acc[j] = 0.f;
    if (n < N) {
      int lo = row_ptr[n], hi = row_ptr[n + 1];
      if (lo < hi) {
        int s0 = src_sorted[lo];
        int s1 = (lo + 1 < hi) ? src_sorted[lo + 1] : s0;
        float4 al0 = *reinterpret_cast<const float4*>(&alpha[(long long)lo * 4]);
        float4 al1 = (lo + 1 < hi)
          ? *reinterpret_cast<const float4*>(&alpha[(long long)(lo + 1) * 4]) : fz4;
        const float* hp0 = &h[(long long)s0 * D_DIM];
        const float* hp1 = &h[(long long)s1 * D_DIM];
        float ha0 = hp0[l], ha1 = hp0[64 + l];
        float hb0 = hp1[l], hb1 = hp1[64 + l];
        for (int p = lo; p < hi; p += 2) {
          float4 cal0 = al0, cal1 = al1;
          float ca0 = ha0, ca1 = ha1, cb0 = hb0, cb1 = hb1;
          int np = p + 2;
          if (np < hi) {
            int t0 = src_sorted[np];
            int t1 = (np + 1 < hi) ? src_sorted[np + 1] : t0;
            al0 = *reinterpret_cast<const float4*>(&alpha[(long long)np * 4]);
            al1 = (np + 1 < hi)
              ? *reinterpret_cast<const float4*>(&alpha[(long long)(np + 1) * 4]) : fz4;
            const float* q0 = &h[(long long)t0 * D_DIM];
            const float* q1 = &h[(long long)t1 * D_DIM];
            ha0 = q0[l]; ha1 = q0[64 + l];
            hb0 = q1[l]; hb1 = q1[64 + l];
          }
          acc[0] = fmaf(cal0.x, ca0, acc[0]); acc[1] = fmaf(cal0.x, ca1, acc[1]);
          acc[2] = fmaf(cal0.y, ca0, acc[2]); acc[3] = fmaf(cal0.y, ca1, acc[3]);
          acc[4] = fmaf(cal0.z, ca0, acc[4]); acc[5] = fmaf(cal0.z, ca1, acc[5]);
          acc[6] = fmaf(cal0.w, ca0, acc[6]); acc[7] = fmaf(cal0.w, ca1, acc[7]);
          acc[0] = fmaf(cal1.x, cb0, acc[0]); acc[1] = fmaf(cal1.x, cb1, acc[1]);
          acc[2] = fmaf(cal1.y, cb0, acc[2]); acc[3] = fmaf(cal1.y, cb1, acc[3]);
          acc[4] = fmaf(cal1.z, cb0, acc[4]); acc[5] = fmaf(cal1.z, cb1, acc[5]);
          acc[6] = fmaf(cal1.w, cb0, acc[6]); acc[7] = fmaf(cal1.w, cb1, acc[7]);
        }
        // deferred softmax normalization
        float4 rc = *reinterpret_cast<const float4*>(&recip[(long long)n * 4]);
        acc[0] *= rc.x; acc[1] *= rc.x;
        acc[2] *= rc.y; acc[3] *= rc.y;
        acc[4] *= rc.z; acc[5] *= rc.z;
        acc[6] *= rc.w; acc[7] *= rc.w;
      }
    }
    int swz = ln & 7;
#pragma unroll
    for (int hd = 0; hd < 4; ++hd) {
      int idx0 = hd * 128 + l;
      int idx1 = hd * 128 + 64 + l;
      int sw0 = ((((idx0 >> 3) ^ swz) << 3) | (idx0 & 7));
      int sw1 = ((((idx1 >> 3) ^ swz) << 3) | (idx1 & 7));
      t_lds[ln * 512 + sw0] = f2bf(acc[2 * hd]);
      t_lds[ln * 512 + sw1] = f2bf(acc[2 * hd + 1]);
    }
  }
  __syncthreads();

  // ---- phase 2: GEMM 32x512 @ 512x128, wave wv owns dg = wv ----
  int cq = l & 15;
  int ksl = l >> 4;
  int dg = wv;
  f32x4 zero4 = {0.f, 0.f, 0.f, 0.f};
  f32x4 acc2[2];
  acc2[0] = zero4; acc2[1] = zero4;

  for (int kc = 0; kc < 16; ++kc) {
    s16x8 a0, a1;
    {
      int r0 = cq;
      int r1 = 16 + cq;
      int idx = kc * 32 + 8 * ksl;                 // 16B-aligned
      int sw0 = ((idx >> 3) ^ (r0 & 7)) << 3;
      int sw1 = ((idx >> 3) ^ (r1 & 7)) << 3;
      a0 = *reinterpret_cast<const s16x8*>(&t_lds[r0 * 512 + sw0]);
      a1 = *reinterpret_cast<const s16x8*>(&t_lds[r1 * 512 + sw1]);
    }
    s16x8 b = *reinterpret_cast<const s16x8*>(&ww_pk[((long long)(kc * 8 + dg) * 64 + l) * 8]);
    acc2[0] = __builtin_amdgcn_mfma_f32_16x16x32_bf16(a0, b, acc2[0], 0, 0, 0);
    acc2[1] = __builtin_amdgcn_mfma_f32_16x16x32_bf16(a1, b, acc2[1], 0, 0, 0);
  }

  float pa = prelu_a[0];
  int col = 16 * dg + cq;
  float bsv = b_w[col] + b_w[128 + col] + b_w[256 + col] + b_w[384 + col];
#pragma unroll
  for (int rg = 0; rg < 2; ++rg)
#pragma unroll
    for (int i = 0; i < 4; ++i) {
      int row = n0 + rg * 16 + 4 * ksl + i;
      if (row >= N) continue;
      bool has = row_ptr[row + 1] > row_ptr[row];
      float v = (acc2[rg][i] + bsv) * 0.25f;
      v = (v >= 0.f) ? v : pa * v;
      if (!has) v = h[(long long)row * 128 + col];
      out[(long long)row * 128 + col] = v;
    }
}

extern "C" void kernel_launch(void* const* d_in, const int* in_sizes, int n_in,
                              void* d_out, int out_size, void* d_ws, size_t ws_size,
                              hipStream_t stream)
{
  const float* h         = (const float*)d_in[0];
  const float* edge_feat = (const float*)d_in[1];
  const int*   src       = (const int*)d_in[2];
  const int*   dst       = (const int*)d_in[3];
  const float* W_rel     = (const float*)d_in[4];
  const float* b_rel     = (const float*)d_in[5];
  const float* ln_g      = (const float*)d_in[6];
  const float* ln_b      = (const float*)d_in[7];
  const float* W_att     = (const float*)d_in[8];
  const float* b_att     = (const float*)d_in[9];
  const float* W_w       = (const float*)d_in[10];
  const float* b_w       = (const float*)d_in[11];
  const float* prelu_a   = (const float*)d_in[12];

  int N = in_sizes[0] / D_DIM;
  int E = in_sizes[2];
  int nb = (N + 1023) / 1024;

  char* ws = (char*)d_ws;
  size_t off = 0;
#define ALLOC(ptr, type, count) type* ptr = (type*)(ws + off); off = (off + (size_t)(count) * sizeof(type) + 63) & ~(size_t)63;
  ALLOC(u_sorted, float, (size_t)E * 4)
  ALLOC(a12, float, (size_t)N * 8)
  ALLOC(recip, float, (size_t)N * 4)
  ALLOC(row_ptr, int, N + 1)
  ALLOC(cnt, int, N)
  ALLOC(rank, int, E)
  ALLOC(src_sorted, int, E)
  ALLOC(wrel_pk, unsigned short, 8192)
  ALLOC(ww_pk, unsigned short, 65536)
  ALLOC(bsum, int, 64)
#undef ALLOC

  int natt_blocks = (N + 3) / 4;
  int prep_threads = 73728 + (N + 3) / 4;
  int prep_blocks = (prep_threads + 255) / 256;
  setup_kernel<<<natt_blocks + prep_blocks, 256, 0, stream>>>(
      h, W_att, W_rel, W_w, a12, wrel_pk, ww_pk, cnt, N, natt_blocks);
  hist_kernel<<<(E + 255) / 256, 256, 0, stream>>>(dst, cnt, rank, E);
  scan1_kernel<<<nb, 256, 0, stream>>>(cnt, bsum, N);
  scan3_kernel<<<nb, 256, 0, stream>>>(cnt, bsum, row_ptr, N, nb);
  edge_mfma_kernel<<<(E + 127) / 128, 512, 0, stream>>>(edge_feat, src, dst, rank, row_ptr,
                                                        wrel_pk, b_rel, ln_g, ln_b,
                                                        W_att, b_att, a12,
                                                        src_sorted, u_sorted, E);
  alpha_kernel<<<(N + 255) / 256, 256, 0, stream>>>(row_ptr, u_sorted, recip, N);
  agg_final_kernel<<<(N + 31) / 32, 512, 0, stream>>>(h, src_sorted, u_sorted, recip, row_ptr,
                                                      ww_pk, b_w, prelu_a, (float*)d_out, N);
}